// Round 3
// baseline (396.056 us; speedup 1.0000x reference)
//
#include <hip/hip_runtime.h>

#define BS 4096
#define IN_DIM 2048
#define NFFT 16384
#define TOTAL_D 129
#define SLACK 64
#define KF 128          // GEMM feature count (DC handled separately)
#define NPROJ 160       // padded proj cols (129 -> 160 = 10 n-tiles)
#define SPLITK 8

#define INV_N_SQRT 0.0078125f            // 1/128
#define SC_PAIR 0.011048543456039804f    // sqrt(2)/128
#define TWO_PI_OVER_N 3.8349519697141029e-4f

typedef __attribute__((ext_vector_type(8))) short bf16x8;
typedef __attribute__((ext_vector_type(4))) float f32x4;

__device__ __forceinline__ ushort f2bf(float f) {
    union { float f; unsigned u; } v; v.f = f;
    unsigned r = v.u + 0x7fffu + ((v.u >> 16) & 1u);   // round-nearest-even
    return (ushort)(r >> 16);
}

// ---------------------------------------------------------------------------
// Basis: Bb[t][k] bf16, k in [0,128). k<64: pure cos/sin of f=k/2+1 (exact
// integer phase); k>=64: Ws[t][k-64]. Scales folded into hs features.
// ---------------------------------------------------------------------------
__global__ __launch_bounds__(256) void k_basis(const float* __restrict__ Ws,
                                               ushort* __restrict__ Bb) {
    int idx = blockIdx.x * 256 + threadIdx.x;    // 16384*16 work items
    int t = idx >> 4, g = idx & 15;
    ushort r[8];
    if (g < 8) {
#pragma unroll
        for (int p = 0; p < 4; ++p) {
            int f = 4 * g + p + 1;                       // 1..32
            int phase = (f * t) & (NFFT - 1);
            float ang = (float)phase * TWO_PI_OVER_N;
            float sv, cv;
            __sincosf(ang, &sv, &cv);
            r[2 * p] = f2bf(cv);
            r[2 * p + 1] = f2bf(sv);
        }
    } else {
        const float* w = &Ws[(size_t)t * SLACK + (g - 8) * 8];
        float4 w0 = *(const float4*)w;
        float4 w1 = *(const float4*)(w + 4);
        r[0] = f2bf(w0.x); r[1] = f2bf(w0.y); r[2] = f2bf(w0.z); r[3] = f2bf(w0.w);
        r[4] = f2bf(w1.x); r[5] = f2bf(w1.y); r[6] = f2bf(w1.z); r[7] = f2bf(w1.w);
    }
    ushort4 lo = {r[0], r[1], r[2], r[3]};
    ushort4 hi = {r[4], r[5], r[6], r[7]};
    ushort* dst = &Bb[(size_t)t * KF + g * 8];
    *(ushort4*)dst = lo;
    *(ushort4*)(dst + 4) = hi;
}

// ---------------------------------------------------------------------------
// Proj GEMM: h_part[kz][b][c] = sum_{k in split kz} x[b][k] * W[min(c,128)][k]
// bf16 MFMA 16x16x32, tile 128x160, 4 waves of 64x80 (4x5 frags), BK=32.
// SPLITK=8 -> 256 blocks = full CU coverage.
// ---------------------------------------------------------------------------
__global__ __launch_bounds__(256, 2) void k_proj(const float* __restrict__ x,
                                                 const float* __restrict__ W,
                                                 float* __restrict__ hp) {
    __shared__ ushort As[128 * 40];   // stride 40 bf16 = 20 words: <=2-way banks
    __shared__ ushort Bs[160 * 40];
    const int tid = threadIdx.x;
    const int lane = tid & 63, wave = tid >> 6;
    const int quad = lane >> 4, m = lane & 15;
    const int wm = wave & 1, wn = wave >> 1;
    const int r0 = blockIdx.x * 128;
    const int kbase = blockIdx.y * (IN_DIM / SPLITK);

    f32x4 acc[4][5];
#pragma unroll
    for (int i = 0; i < 4; ++i)
#pragma unroll
        for (int j = 0; j < 5; ++j) acc[i][j] = 0.f;

    for (int ch = 0; ch < IN_DIM / SPLITK / 32; ++ch) {
        const int kb = kbase + ch * 32;
        // stage x tile 128x32 (fp32 -> bf16)
#pragma unroll
        for (int it = 0; it < 4; ++it) {
            int v = tid + it * 256;
            int row = v >> 3, c = v & 7;
            float4 xv = *(const float4*)&x[(size_t)(r0 + row) * IN_DIM + kb + c * 4];
            ushort4 o = {f2bf(xv.x), f2bf(xv.y), f2bf(xv.z), f2bf(xv.w)};
            *(ushort4*)&As[row * 40 + c * 4] = o;
        }
        // stage W tile 160x32 (rows >=129 clamped; results discarded later)
#pragma unroll
        for (int it = 0; it < 5; ++it) {
            int v = tid + it * 256;
            int row = v >> 3, c = v & 7;
            int rw = row < TOTAL_D ? row : TOTAL_D - 1;
            float4 wv = *(const float4*)&W[(size_t)rw * IN_DIM + kb + c * 4];
            ushort4 o = {f2bf(wv.x), f2bf(wv.y), f2bf(wv.z), f2bf(wv.w)};
            *(ushort4*)&Bs[row * 40 + c * 4] = o;
        }
        __syncthreads();
        bf16x8 af[4], bfr[5];
#pragma unroll
        for (int i = 0; i < 4; ++i)
            af[i] = *(const bf16x8*)&As[(wm * 64 + i * 16 + m) * 40 + quad * 8];
#pragma unroll
        for (int j = 0; j < 5; ++j)
            bfr[j] = *(const bf16x8*)&Bs[(wn * 80 + j * 16 + m) * 40 + quad * 8];
#pragma unroll
        for (int i = 0; i < 4; ++i)
#pragma unroll
            for (int j = 0; j < 5; ++j)
                acc[i][j] = __builtin_amdgcn_mfma_f32_16x16x32_bf16(af[i], bfr[j], acc[i][j], 0, 0, 0);
        __syncthreads();
    }
    // epilogue: C/D layout col=lane&15, row=quad*4+reg
#pragma unroll
    for (int i = 0; i < 4; ++i)
#pragma unroll
        for (int reg = 0; reg < 4; ++reg) {
            int row = r0 + wm * 64 + i * 16 + quad * 4 + reg;
            float* orow = &hp[((size_t)blockIdx.y * BS + row) * NPROJ + wn * 80 + m];
#pragma unroll
            for (int j = 0; j < 5; ++j) orow[j * 16] = acc[i][j][reg];
        }
}

// ---------------------------------------------------------------------------
// Finalize: sum split-K partials + bias -> dc0 (fp32, pre-scaled by 1/128)
// and scaled bf16 features hs[b][k]  (k<64: *sqrt2/128 ; k>=64: slack as-is)
// ---------------------------------------------------------------------------
__global__ __launch_bounds__(256) void k_finalize(const float* __restrict__ hp,
                                                  const float* __restrict__ bvec,
                                                  float* __restrict__ dc0,
                                                  ushort* __restrict__ hs) {
    int b = blockIdx.x * 256 + threadIdx.x;   // 0..4095
    int g = blockIdx.y;                       // 0..16 (cols 8g..8g+7, used c<=128)
    int c0 = g * 8;
    float v[8];
#pragma unroll
    for (int e = 0; e < 8; ++e) v[e] = 0.f;
#pragma unroll
    for (int s = 0; s < SPLITK; ++s) {
        const float* p = &hp[((size_t)s * BS + b) * NPROJ + c0];
        float4 p0 = *(const float4*)p;
        float4 p1 = *(const float4*)(p + 4);
        v[0] += p0.x; v[1] += p0.y; v[2] += p0.z; v[3] += p0.w;
        v[4] += p1.x; v[5] += p1.y; v[6] += p1.z; v[7] += p1.w;
    }
#pragma unroll
    for (int e = 0; e < 8; ++e) {
        int c = c0 + e;
        if (c >= TOTAL_D) break;
        float val = v[e] + bvec[c];
        if (c == 0) {
            dc0[b] = val * INV_N_SQRT;
        } else {
            int k = c - 1;
            float sc = (k < 64) ? SC_PAIR : 1.f;
            hs[(size_t)b * KF + k] = f2bf(val * sc);
        }
    }
}

// ---------------------------------------------------------------------------
// Main GEMM: out[b][t] = dc0[b] + sum_k hs[b][k]*Bb[t][k]
// r0 LDS structure + TILE AGGREGATION: each block owns one b-tile (hs staged
// ONCE, persistent in Bs) and loops over 4 t-tiles (Bb re-staged into As per
// iteration). Staging traffic: 256 MB -> 160 MB (hs re-reads 128x -> 32x).
// Next tile's Bb loads are issued before the current MFMA cluster (8 uint4 in
// flight); stores of tile i overlap loads of tile i+1. XCD-chunked bijective
// swizzle: each XCD covers 4 t-groups x all b -> 512KB Bb + 1MB hs, L2-fit.
// OPERAND-SWAPPED: MFMA-M = t, MFMA-N = b; each acc f32x4 is a direct
// dwordx4 store, 4 quads of a quarter-wave complete a 64B line.
// ---------------------------------------------------------------------------
__global__ __launch_bounds__(256, 2) void k_main(const ushort* __restrict__ hs,
                                                 const float* __restrict__ dc0,
                                                 const ushort* __restrict__ Bb,
                                                 float* __restrict__ out) {
    __shared__ ushort As[128 * 128];   // basis tile [t_local][k], swizzled, per-iter
    __shared__ ushort Bs[128 * 128];   // hs tile    [b_local][k], swizzled, persistent
    const int tid = threadIdx.x;
    const int lane = tid & 63, wave = tid >> 6;
    const int quad = lane >> 4, m = lane & 15;
    const int wm = wave & 1, wn = wave >> 1;   // wm -> t-half, wn -> b-half

    // XCD-chunked bijective swizzle over 1024 blocks (1024 % 8 == 0):
    // XCD k -> wg in [128k,128k+128) -> tg in [4k,4k+4), all 32 b-tiles.
    int orig = blockIdx.x;                     // 0..1023
    int wg = ((orig & 7) << 7) + (orig >> 3);
    const int b0 = (wg & 31) * 128;
    const int tbase = (wg >> 5) * 512;         // 4 t-tiles of 128

    const int srow = tid >> 4;                 // staging row base (0..15)
    const int sgr = tid & 15;                  // 16B granule index (0..15)

    // prologue: stage hs (persistent) + Bb tile 0
    uint4 rh[8], rb[8];
#pragma unroll
    for (int it = 0; it < 8; ++it) {
        int row = srow + it * 16;
        rh[it] = *(const uint4*)&hs[((size_t)(b0 + row) << 7) + sgr * 8];
    }
#pragma unroll
    for (int it = 0; it < 8; ++it) {
        int row = srow + it * 16;
        rb[it] = *(const uint4*)&Bb[((size_t)(tbase + row) << 7) + sgr * 8];
    }
#pragma unroll
    for (int it = 0; it < 8; ++it) {
        int row = srow + it * 16;
        int gx = (sgr ^ (row & 7)) * 8;
        *(uint4*)&Bs[(row << 7) + gx] = rh[it];
        *(uint4*)&As[(row << 7) + gx] = rb[it];
    }
    // DC term (depends only on b -> load once, reuse all 4 iterations)
    float dc[4];
#pragma unroll
    for (int j = 0; j < 4; ++j) dc[j] = dc0[b0 + wn * 64 + j * 16 + m];
    __syncthreads();

#pragma unroll 1
    for (int i = 0; i < 4; ++i) {
        const int t0 = tbase + i * 128;
        // issue next Bb tile's loads early (overlap with MFMA below)
        if (i < 3) {
#pragma unroll
            for (int it = 0; it < 8; ++it) {
                int row = srow + it * 16;
                rb[it] = *(const uint4*)&Bb[((size_t)(t0 + 128 + row) << 7) + sgr * 8];
            }
        }

        f32x4 acc[4][4];
#pragma unroll
        for (int j = 0; j < 4; ++j)
#pragma unroll
            for (int ii = 0; ii < 4; ++ii) acc[ii][j] = dc[j];

#pragma unroll
        for (int ks = 0; ks < 4; ++ks) {
            bf16x8 af[4], bfr[4];
#pragma unroll
            for (int ii = 0; ii < 4; ++ii) {
                int row = wm * 64 + ii * 16 + m;
                af[ii] = *(const bf16x8*)&As[(row << 7) + (((ks * 4 + quad) ^ (row & 7)) * 8)];
            }
#pragma unroll
            for (int j = 0; j < 4; ++j) {
                int row = wn * 64 + j * 16 + m;
                bfr[j] = *(const bf16x8*)&Bs[(row << 7) + (((ks * 4 + quad) ^ (row & 7)) * 8)];
            }
#pragma unroll
            for (int ii = 0; ii < 4; ++ii)
#pragma unroll
                for (int j = 0; j < 4; ++j)
                    acc[ii][j] = __builtin_amdgcn_mfma_f32_16x16x32_bf16(af[ii], bfr[j], acc[ii][j], 0, 0, 0);
        }

        // epilogue for this t-tile: quads complete 64B lines
#pragma unroll
        for (int j = 0; j < 4; ++j) {
            size_t rowb = (size_t)(b0 + wn * 64 + j * 16 + m);
            float* orow = out + rowb * NFFT + t0 + wm * 64 + quad * 4;
#pragma unroll
            for (int ii = 0; ii < 4; ++ii)
                *(f32x4*)&orow[ii * 16] = acc[ii][j];
        }

        if (i < 3) {
            __syncthreads();   // all waves done reading As(i)
#pragma unroll
            for (int it = 0; it < 8; ++it) {
                int row = srow + it * 16;
                *(uint4*)&As[(row << 7) + ((sgr ^ (row & 7)) * 8)] = rb[it];
            }
            __syncthreads();   // As(i+1) visible
        }
    }
}

extern "C" void kernel_launch(void* const* d_in, const int* in_sizes, int n_in,
                              void* d_out, int out_size, void* d_ws, size_t ws_size,
                              hipStream_t stream) {
    const float* x   = (const float*)d_in[0];
    const float* W   = (const float*)d_in[1];
    const float* b   = (const float*)d_in[2];
    const float* Wsl = (const float*)d_in[3];
    float* out = (float*)d_out;

    char* ws = (char*)d_ws;
    float*  h_part = (float*)ws;                        // 8*4096*160*4 = 21.0 MB
    ushort* Bb     = (ushort*)(ws + 20971520);          // 16384*128*2  =  4.0 MB
    ushort* hs     = (ushort*)(ws + 25165824);          // 4096*128*2   =  1.0 MB
    float*  dc0    = (float*)(ws + 26214400);           // 4096*4       = 16 KB

    k_basis<<<NFFT * 16 / 256, 256, 0, stream>>>(Wsl, Bb);
    k_proj<<<dim3(BS / 128, SPLITK), 256, 0, stream>>>(x, W, h_part);
    k_finalize<<<dim3(BS / 256, 17), 256, 0, stream>>>(h_part, b, dc0, hs);
    k_main<<<BS / 128 * (NFFT / 512), 256, 0, stream>>>(hs, dc0, Bb, out);
}

// Round 4
// 354.764 us; speedup vs baseline: 1.1164x; 1.1164x over previous
//
#include <hip/hip_runtime.h>

#define BS 4096
#define IN_DIM 2048
#define NFFT 16384
#define TOTAL_D 129
#define SLACK 64
#define KF 128          // GEMM feature count (DC handled separately)
#define NPROJ 160       // padded proj cols (129 -> 160 = 10 n-tiles)
#define SPLITK 8

#define INV_N_SQRT 0.0078125f            // 1/128
#define SC_PAIR 0.011048543456039804f    // sqrt(2)/128
#define TWO_PI_OVER_N 3.8349519697141029e-4f

typedef __attribute__((ext_vector_type(8))) short bf16x8;
typedef __attribute__((ext_vector_type(4))) float f32x4;

__device__ __forceinline__ ushort f2bf(float f) {
    union { float f; unsigned u; } v; v.f = f;
    unsigned r = v.u + 0x7fffu + ((v.u >> 16) & 1u);   // round-nearest-even
    return (ushort)(r >> 16);
}

// ---------------------------------------------------------------------------
// Basis: Bb[t][k] bf16, k in [0,128). k<64: pure cos/sin of f=k/2+1 (exact
// integer phase); k>=64: Ws[t][k-64]. Scales folded into hs features.
// ---------------------------------------------------------------------------
__global__ __launch_bounds__(256) void k_basis(const float* __restrict__ Ws,
                                               ushort* __restrict__ Bb) {
    int idx = blockIdx.x * 256 + threadIdx.x;    // 16384*16 work items
    int t = idx >> 4, g = idx & 15;
    ushort r[8];
    if (g < 8) {
#pragma unroll
        for (int p = 0; p < 4; ++p) {
            int f = 4 * g + p + 1;                       // 1..32
            int phase = (f * t) & (NFFT - 1);
            float ang = (float)phase * TWO_PI_OVER_N;
            float sv, cv;
            __sincosf(ang, &sv, &cv);
            r[2 * p] = f2bf(cv);
            r[2 * p + 1] = f2bf(sv);
        }
    } else {
        const float* w = &Ws[(size_t)t * SLACK + (g - 8) * 8];
        float4 w0 = *(const float4*)w;
        float4 w1 = *(const float4*)(w + 4);
        r[0] = f2bf(w0.x); r[1] = f2bf(w0.y); r[2] = f2bf(w0.z); r[3] = f2bf(w0.w);
        r[4] = f2bf(w1.x); r[5] = f2bf(w1.y); r[6] = f2bf(w1.z); r[7] = f2bf(w1.w);
    }
    ushort4 lo = {r[0], r[1], r[2], r[3]};
    ushort4 hi = {r[4], r[5], r[6], r[7]};
    ushort* dst = &Bb[(size_t)t * KF + g * 8];
    *(ushort4*)dst = lo;
    *(ushort4*)(dst + 4) = hi;
}

// ---------------------------------------------------------------------------
// Proj GEMM: h_part[kz][b][c] = sum_{k in split kz} x[b][k] * W[min(c,128)][k]
// bf16 MFMA 16x16x32, tile 128x160, 4 waves of 64x80 (4x5 frags), BK=32.
// SPLITK=8 -> 256 blocks = full CU coverage.
// ---------------------------------------------------------------------------
__global__ __launch_bounds__(256, 2) void k_proj(const float* __restrict__ x,
                                                 const float* __restrict__ W,
                                                 float* __restrict__ hp) {
    __shared__ ushort As[128 * 40];   // stride 40 bf16 = 20 words: <=2-way banks
    __shared__ ushort Bs[160 * 40];
    const int tid = threadIdx.x;
    const int lane = tid & 63, wave = tid >> 6;
    const int quad = lane >> 4, m = lane & 15;
    const int wm = wave & 1, wn = wave >> 1;
    const int r0 = blockIdx.x * 128;
    const int kbase = blockIdx.y * (IN_DIM / SPLITK);

    f32x4 acc[4][5];
#pragma unroll
    for (int i = 0; i < 4; ++i)
#pragma unroll
        for (int j = 0; j < 5; ++j) acc[i][j] = 0.f;

    for (int ch = 0; ch < IN_DIM / SPLITK / 32; ++ch) {
        const int kb = kbase + ch * 32;
        // stage x tile 128x32 (fp32 -> bf16)
#pragma unroll
        for (int it = 0; it < 4; ++it) {
            int v = tid + it * 256;
            int row = v >> 3, c = v & 7;
            float4 xv = *(const float4*)&x[(size_t)(r0 + row) * IN_DIM + kb + c * 4];
            ushort4 o = {f2bf(xv.x), f2bf(xv.y), f2bf(xv.z), f2bf(xv.w)};
            *(ushort4*)&As[row * 40 + c * 4] = o;
        }
        // stage W tile 160x32 (rows >=129 clamped; results discarded later)
#pragma unroll
        for (int it = 0; it < 5; ++it) {
            int v = tid + it * 256;
            int row = v >> 3, c = v & 7;
            int rw = row < TOTAL_D ? row : TOTAL_D - 1;
            float4 wv = *(const float4*)&W[(size_t)rw * IN_DIM + kb + c * 4];
            ushort4 o = {f2bf(wv.x), f2bf(wv.y), f2bf(wv.z), f2bf(wv.w)};
            *(ushort4*)&Bs[row * 40 + c * 4] = o;
        }
        __syncthreads();
        bf16x8 af[4], bfr[5];
#pragma unroll
        for (int i = 0; i < 4; ++i)
            af[i] = *(const bf16x8*)&As[(wm * 64 + i * 16 + m) * 40 + quad * 8];
#pragma unroll
        for (int j = 0; j < 5; ++j)
            bfr[j] = *(const bf16x8*)&Bs[(wn * 80 + j * 16 + m) * 40 + quad * 8];
#pragma unroll
        for (int i = 0; i < 4; ++i)
#pragma unroll
            for (int j = 0; j < 5; ++j)
                acc[i][j] = __builtin_amdgcn_mfma_f32_16x16x32_bf16(af[i], bfr[j], acc[i][j], 0, 0, 0);
        __syncthreads();
    }
    // epilogue: C/D layout col=lane&15, row=quad*4+reg
#pragma unroll
    for (int i = 0; i < 4; ++i)
#pragma unroll
        for (int reg = 0; reg < 4; ++reg) {
            int row = r0 + wm * 64 + i * 16 + quad * 4 + reg;
            float* orow = &hp[((size_t)blockIdx.y * BS + row) * NPROJ + wn * 80 + m];
#pragma unroll
            for (int j = 0; j < 5; ++j) orow[j * 16] = acc[i][j][reg];
        }
}

// ---------------------------------------------------------------------------
// Finalize: sum split-K partials + bias -> dc0 (fp32, pre-scaled by 1/128)
// and scaled bf16 features hs[b][k]  (k<64: *sqrt2/128 ; k>=64: slack as-is)
// ---------------------------------------------------------------------------
__global__ __launch_bounds__(256) void k_finalize(const float* __restrict__ hp,
                                                  const float* __restrict__ bvec,
                                                  float* __restrict__ dc0,
                                                  ushort* __restrict__ hs) {
    int b = blockIdx.x * 256 + threadIdx.x;   // 0..4095
    int g = blockIdx.y;                       // 0..16 (cols 8g..8g+7, used c<=128)
    int c0 = g * 8;
    float v[8];
#pragma unroll
    for (int e = 0; e < 8; ++e) v[e] = 0.f;
#pragma unroll
    for (int s = 0; s < SPLITK; ++s) {
        const float* p = &hp[((size_t)s * BS + b) * NPROJ + c0];
        float4 p0 = *(const float4*)p;
        float4 p1 = *(const float4*)(p + 4);
        v[0] += p0.x; v[1] += p0.y; v[2] += p0.z; v[3] += p0.w;
        v[4] += p1.x; v[5] += p1.y; v[6] += p1.z; v[7] += p1.w;
    }
#pragma unroll
    for (int e = 0; e < 8; ++e) {
        int c = c0 + e;
        if (c >= TOTAL_D) break;
        float val = v[e] + bvec[c];
        if (c == 0) {
            dc0[b] = val * INV_N_SQRT;
        } else {
            int k = c - 1;
            float sc = (k < 64) ? SC_PAIR : 1.f;
            hs[(size_t)b * KF + k] = f2bf(val * sc);
        }
    }
}

// ---------------------------------------------------------------------------
// Main GEMM: out[b][t] = dc0[b] + sum_k hs[b][k]*Bb[t][k]
// EXACT r0 structure (proven 335.6 us) + two surgical L2 changes:
//  (1) non-temporal stores for out (write-only stream stops evicting Bb/hs)
//  (2) XCD-chunked bijective block remap: xcd = flat&7 owns 16 contiguous
//      t-tiles (512 KB Bb) x all 32 b-tiles (1 MB hs) -> 1.5 MB per-XCD
//      working set, L2-resident; staging re-reads become L2 hits.
// OPERAND-SWAPPED: MFMA-M = t, MFMA-N = b; each acc f32x4 is a direct
// dwordx4 store, 4 quads of a quarter-wave complete a 64B line.
// ---------------------------------------------------------------------------
__global__ __launch_bounds__(256, 2) void k_main(const ushort* __restrict__ hs,
                                                 const float* __restrict__ dc0,
                                                 const ushort* __restrict__ Bb,
                                                 float* __restrict__ out) {
    __shared__ ushort As[128 * 128];   // basis tile [t_local][k], swizzled
    __shared__ ushort Bs[128 * 128];   // hs tile    [b_local][k], swizzled
    const int tid = threadIdx.x;
    const int lane = tid & 63, wave = tid >> 6;
    const int quad = lane >> 4, m = lane & 15;
    const int wm = wave & 1, wn = wave >> 1;   // wm -> t-half, wn -> b-half

    // XCD-chunked bijective remap of flat block id (4096 blocks, 4096%8==0):
    // orig&7 = XCD (round-robin dispatch); each XCD covers tx in
    // [xcd*16, xcd*16+16) x all by. Per-XCD L2 set: 512KB Bb + 1MB hs.
    int orig = blockIdx.y * 128 + blockIdx.x;
    int xcd = orig & 7, idx = orig >> 3;
    int tx = xcd * 16 + (idx & 15);
    int by = idx >> 4;
    const int t0 = tx * 128;
    const int b0 = by * 128;

    // stage basis (A) and hs (B), XOR-swizzled so frag reads are <=2-way
#pragma unroll
    for (int it = 0; it < 8; ++it) {
        int v = tid + it * 256;
        int row = v >> 4, g = v & 15;
        uint4 d = *(const uint4*)&Bb[((size_t)(t0 + row) << 7) + g * 8];
        *(uint4*)&As[(row << 7) + ((g ^ (row & 7)) * 8)] = d;
    }
#pragma unroll
    for (int it = 0; it < 8; ++it) {
        int v = tid + it * 256;
        int row = v >> 4, g = v & 15;
        uint4 d = *(const uint4*)&hs[((size_t)(b0 + row) << 7) + g * 8];
        *(uint4*)&Bs[(row << 7) + ((g ^ (row & 7)) * 8)] = d;
    }

    // DC term as C-init: per-lane scalar broadcast of dc0[b]
    f32x4 acc[4][4];
#pragma unroll
    for (int j = 0; j < 4; ++j) {
        float d = dc0[b0 + wn * 64 + j * 16 + m];
#pragma unroll
        for (int i = 0; i < 4; ++i) acc[i][j] = d;
    }
    __syncthreads();

#pragma unroll
    for (int ks = 0; ks < 4; ++ks) {
        bf16x8 af[4], bfr[4];
#pragma unroll
        for (int i = 0; i < 4; ++i) {
            int row = wm * 64 + i * 16 + m;
            af[i] = *(const bf16x8*)&As[(row << 7) + (((ks * 4 + quad) ^ (row & 7)) * 8)];
        }
#pragma unroll
        for (int j = 0; j < 4; ++j) {
            int row = wn * 64 + j * 16 + m;
            bfr[j] = *(const bf16x8*)&Bs[(row << 7) + (((ks * 4 + quad) ^ (row & 7)) * 8)];
        }
#pragma unroll
        for (int i = 0; i < 4; ++i)
#pragma unroll
            for (int j = 0; j < 4; ++j)
                acc[i][j] = __builtin_amdgcn_mfma_f32_16x16x32_bf16(af[i], bfr[j], acc[i][j], 0, 0, 0);
    }

    // epilogue: 16 NT dwordx4 stores per thread, quads complete 64B lines
#pragma unroll
    for (int j = 0; j < 4; ++j) {
        size_t rowb = (size_t)(b0 + wn * 64 + j * 16 + m);
        float* orow = out + rowb * NFFT + t0 + wm * 64 + quad * 4;
#pragma unroll
        for (int i = 0; i < 4; ++i)
            __builtin_nontemporal_store(acc[i][j], (f32x4*)&orow[i * 16]);
    }
}

extern "C" void kernel_launch(void* const* d_in, const int* in_sizes, int n_in,
                              void* d_out, int out_size, void* d_ws, size_t ws_size,
                              hipStream_t stream) {
    const float* x   = (const float*)d_in[0];
    const float* W   = (const float*)d_in[1];
    const float* b   = (const float*)d_in[2];
    const float* Wsl = (const float*)d_in[3];
    float* out = (float*)d_out;

    char* ws = (char*)d_ws;
    float*  h_part = (float*)ws;                        // 8*4096*160*4 = 21.0 MB
    ushort* Bb     = (ushort*)(ws + 20971520);          // 16384*128*2  =  4.0 MB
    ushort* hs     = (ushort*)(ws + 25165824);          // 4096*128*2   =  1.0 MB
    float*  dc0    = (float*)(ws + 26214400);           // 4096*4       = 16 KB

    k_basis<<<NFFT * 16 / 256, 256, 0, stream>>>(Wsl, Bb);
    k_proj<<<dim3(BS / 128, SPLITK), 256, 0, stream>>>(x, W, h_part);
    k_finalize<<<dim3(BS / 256, 17), 256, 0, stream>>>(h_part, b, dc0, hs);
    k_main<<<dim3(NFFT / 128, BS / 128), 256, 0, stream>>>(hs, dc0, Bb, out);
}